// Round 1
// baseline (93.746 us; speedup 1.0000x reference)
//
#include <hip/hip_runtime.h>

#define NN   10000   // nodes
#define NASD 64      // anchors
#define FD   64      // features
#define OD   64      // outputs

// One wave handles one node n per grid-stride iteration.
//   gather phase: g[b,f] = (1/64) * sum_a d[n,a] * x[idx[n,a], b, f]
//   dot phase   : out[n,b,o] = sum_k u[b,k] * W[o,k] + bias[o],  u = [g | x[n]]
__launch_bounds__(256, 4)
__global__ void pgnn_kernel(const float* __restrict__ x,
                            const float* __restrict__ dmax,
                            const int*   __restrict__ amax,
                            const float* __restrict__ W,
                            const float* __restrict__ bias,
                            float*       __restrict__ out,
                            int nWavesTotal) {
    // W rows padded to 129 floats: lane o reads W[o*129+k]; banks (o+k)%32 -> 2-way (free)
    __shared__ float Wlds[OD * 129];
    __shared__ float blds[OD];
    __shared__ float ulds[4][256];   // per-wave u buffer: [k][b] interleaved, k=0..127, b=0..1

    const int tid  = threadIdx.x;
    const int lane = tid & 63;
    const int w    = tid >> 6;

    // stage W + bias (block-cooperative, coalesced reads)
    for (int j = tid; j < OD * 128; j += 256) {
        int o = j >> 7, k = j & 127;
        Wlds[o * 129 + k] = W[j];
    }
    if (tid < OD) blds[tid] = bias[tid];
    __syncthreads();

    float* u = ulds[w];
    const int e0 = lane * 2, e1 = lane * 2 + 1;   // element ids in the 128-float [b][f] block

    for (int n = blockIdx.x * 4 + w; n < NN; n += nWavesTotal) {
        // ---------------- gather phase ----------------
        float dv = dmax[n * 64 + lane];
        int   iv = amax[n * 64 + lane];
        float g0 = 0.f, g1 = 0.f;
        #pragma unroll 8
        for (int a = 0; a < 64; ++a) {
            int   mm = __builtin_amdgcn_readlane(iv, a);                       // SGPR node id
            float dd = __uint_as_float(__builtin_amdgcn_readlane(__float_as_uint(dv), a));
            const float2 xv = *reinterpret_cast<const float2*>(x + mm * 128 + e0);
            g0 = fmaf(dd, xv.x, g0);
            g1 = fmaf(dd, xv.y, g1);
        }
        g0 *= (1.0f / 64.0f);
        g1 *= (1.0f / 64.0f);

        // scatter g into u slots k=f (b-interleaved); lane covers elements e0,e1
        u[(e0 & 63) * 2 + (e0 >> 6)] = g0;
        u[(e1 & 63) * 2 + (e1 >> 6)] = g1;
        // x[n] part -> slots k = 64+f
        const float2 xs = *reinterpret_cast<const float2*>(x + n * 128 + e0);
        u[(64 + (e0 & 63)) * 2 + (e0 >> 6)] = xs.x;
        u[(64 + (e1 & 63)) * 2 + (e1 >> 6)] = xs.y;

        // wave-internal LDS visibility (same-wave cross-lane exchange)
        asm volatile("s_waitcnt lgkmcnt(0)" ::: "memory");
        __builtin_amdgcn_sched_barrier(0);

        // ---------------- dot phase: lane = o ----------------
        float acc0 = blds[lane];
        float acc1 = acc0;
        const float* wrow = &Wlds[lane * 129];
        #pragma unroll 4
        for (int k = 0; k < 128; k += 2) {
            float4 uu = *reinterpret_cast<const float4*>(&u[k * 2]);  // broadcast read (free)
            float w0 = wrow[k], w1 = wrow[k + 1];
            acc0 = fmaf(uu.x, w0, acc0);
            acc1 = fmaf(uu.y, w0, acc1);
            acc0 = fmaf(uu.z, w1, acc0);
            acc1 = fmaf(uu.w, w1, acc1);
        }
        out[n * 128 + lane]      = acc0;   // b=0
        out[n * 128 + 64 + lane] = acc1;   // b=1

        // WAR guard before next iteration overwrites u
        asm volatile("s_waitcnt lgkmcnt(0)" ::: "memory");
        __builtin_amdgcn_sched_barrier(0);
    }
}

extern "C" void kernel_launch(void* const* d_in, const int* in_sizes, int n_in,
                              void* d_out, int out_size, void* d_ws, size_t ws_size,
                              hipStream_t stream) {
    const float* x    = (const float*)d_in[0];   // (N, B, F) = (10000, 2, 64)
    const float* dmax = (const float*)d_in[1];   // (N, 64)
    const int*   amax = (const int*)  d_in[2];   // (N, 64)
    const float* W    = (const float*)d_in[3];   // (64, 128)
    const float* bias = (const float*)d_in[4];   // (64,)
    float* out = (float*)d_out;                  // (N, B, OUT) = (10000, 2, 64)

    const int blocks = 1024;                     // 4 waves/block -> 4096 waves, grid-stride
    pgnn_kernel<<<blocks, 256, 0, stream>>>(x, dmax, amax, W, bias, out, blocks * 4);
}